// Round 2
// baseline (177.549 us; speedup 1.0000x reference)
//
#include <hip/hip_runtime.h>
#include <hip/hip_bf16.h>
#include <math.h>

using bf16 = __hip_bfloat16;
typedef short short8 __attribute__((ext_vector_type(8)));   // 8 bf16 = 4 VGPRs
typedef float f32x4 __attribute__((ext_vector_type(4)));    // MFMA 16x16 acc

#define MFMA16 __builtin_amdgcn_mfma_f32_16x16x32_bf16

#define B_ 8
#define S_ 8192
#define D_ 128

// ---- swizzled LDS addressing: 128x128 bf16 tile, 256B rows of 16 x 16B chunks.
// chunk index XORed with row&15 -> b128 row-column reads spread across banks.
__device__ __forceinline__ int sw(int r, int chunk) {
  return r * 256 + (((chunk) ^ (r & 15)) << 4);
}

__device__ __forceinline__ float gelu_exact(float y) {
  return 0.5f * y * (1.0f + erff(y * 0.70710678118654752f));
}

// ------ weight transpose+convert: Wt[w][n][k] = bf16(W[w][k][n]) -------------
__global__ void transw(const float* __restrict__ wq, const float* __restrict__ wk,
                       const float* __restrict__ wv, const float* __restrict__ wo,
                       bf16* __restrict__ wt) {
  __shared__ float smf[128 * 128];          // 64 KB fp32 tile
  const float* W = (blockIdx.x == 0) ? wq : (blockIdx.x == 1) ? wk
                 : (blockIdx.x == 2) ? wv : wo;
  for (int i = 0; i < 16; ++i) {
    int o = (threadIdx.x + i * 256) * 4;
    *(float4*)(smf + o) = *(const float4*)(W + o);
  }
  __syncthreads();
  int n = threadIdx.x >> 1, k0 = (threadIdx.x & 1) * 64;
  bf16* dst = wt + blockIdx.x * 16384 + n * 128 + k0;
  for (int j = 0; j < 8; ++j) {
    bf16 tmp[8];
    for (int e = 0; e < 8; ++e)
      tmp[e] = __float2bfloat16(smf[(k0 + j * 8 + e) * 128 + n]);
    *(uint4*)(dst + j * 8) = *(const uint4*)tmp;
  }
}

// ---------------- second half: out = gelu(beta[d]) broadcast ------------------
__global__ void fill2(const float* __restrict__ beta, float* __restrict__ out) {
  size_t tid = (size_t)blockIdx.x * 256 + threadIdx.x;
  size_t o = tid * 8;                       // element offset within all 2nd halves
  int b = (int)(o >> 20);                   // 8192*128 = 2^20 per batch half
  size_t r = o & ((size_t)(1 << 20) - 1);
  int d0 = (int)(r & 127);
  float4 b0 = *(const float4*)(beta + d0);
  float4 b1 = *(const float4*)(beta + d0 + 4);
  float4 r0, r1;
  r0.x = gelu_exact(b0.x); r0.y = gelu_exact(b0.y);
  r0.z = gelu_exact(b0.z); r0.w = gelu_exact(b0.w);
  r1.x = gelu_exact(b1.x); r1.y = gelu_exact(b1.y);
  r1.z = gelu_exact(b1.z); r1.w = gelu_exact(b1.w);
  float* op = out + (size_t)b * 2097152 + 1048576 + r;
  *(float4*)op = r0;
  *(float4*)(op + 4) = r1;
}

// ---------------- helpers for the attention kernel ----------------------------
__device__ __forceinline__ void clr(f32x4 acc[2][8]) {
#pragma unroll
  for (int i = 0; i < 2; ++i)
#pragma unroll
    for (int j = 0; j < 8; ++j) acc[i][j] = (f32x4){0.f, 0.f, 0.f, 0.f};
}

// C[128-strip] = A(lds tile, rows row0..row0+31) @ B(global, pre-transposed Wt[n][k])
__device__ __forceinline__ void mm_g16(const char* tA, const char* wB,
                                       int row0, int lane, f32x4 acc[2][8]) {
  int l15 = lane & 15, quad = lane >> 4;
#pragma unroll
  for (int t = 0; t < 4; ++t) {
    short8 a0 = *(const short8*)(tA + sw(row0 + l15,      4 * t + quad));
    short8 a1 = *(const short8*)(tA + sw(row0 + 16 + l15, 4 * t + quad));
#pragma unroll
    for (int ct = 0; ct < 8; ++ct) {
      short8 bb = *(const short8*)(wB + (ct * 16 + l15) * 256 + t * 64 + quad * 16);
      acc[0][ct] = MFMA16(a0, bb, acc[0][ct], 0, 0, 0);
      acc[1][ct] = MFMA16(a1, bb, acc[1][ct], 0, 0, 0);
    }
  }
}

// C = A(lds) @ B(lds, stored [n][k] row-major-swizzled)
__device__ __forceinline__ void mm_l16(const char* tA, const char* tB,
                                       int row0, int lane, f32x4 acc[2][8]) {
  int l15 = lane & 15, quad = lane >> 4;
#pragma unroll
  for (int t = 0; t < 4; ++t) {
    short8 a0 = *(const short8*)(tA + sw(row0 + l15,      4 * t + quad));
    short8 a1 = *(const short8*)(tA + sw(row0 + 16 + l15, 4 * t + quad));
#pragma unroll
    for (int ct = 0; ct < 8; ++ct) {
      short8 bb = *(const short8*)(tB + sw(ct * 16 + l15, 4 * t + quad));
      acc[0][ct] = MFMA16(a0, bb, acc[0][ct], 0, 0, 0);
      acc[1][ct] = MFMA16(a1, bb, acc[1][ct], 0, 0, 0);
    }
  }
}

// write acc (C/D layout) into swizzled lds tile, optional per-row scale
__device__ __forceinline__ void store_tile16(char* tile, int row0, int lane,
                                             const f32x4 acc[2][8],
                                             const float* rowscale) {
  int l15 = lane & 15, quad = lane >> 4;
#pragma unroll
  for (int ct = 0; ct < 8; ++ct) {
    int col = ct * 16 + l15;
#pragma unroll
    for (int rt = 0; rt < 2; ++rt)
#pragma unroll
      for (int r = 0; r < 4; ++r) {
        int row = row0 + rt * 16 + quad * 4 + r;
        float v = acc[rt][ct][r];
        if (rowscale) v *= rowscale[rt * 4 + r];
        *(bf16*)(tile + sw(row, col >> 3) + (col & 7) * 2) = __float2bfloat16(v);
      }
  }
}

// write acc transposed (element (row,col) -> tile[col][row])
__device__ __forceinline__ void store_tileT16(char* tile, int row0, int lane,
                                              const f32x4 acc[2][8]) {
  int l15 = lane & 15, quad = lane >> 4;
#pragma unroll
  for (int ct = 0; ct < 8; ++ct) {
    int col = ct * 16 + l15;
#pragma unroll
    for (int rt = 0; rt < 2; ++rt)
#pragma unroll
      for (int r = 0; r < 4; ++r) {
        int row = row0 + rt * 16 + quad * 4 + r;
        *(bf16*)(tile + sw(col, row >> 3) + (row & 7) * 2) =
            __float2bfloat16(acc[rt][ct][r]);
      }
  }
}

// ---------------- main: per-block attention + LN + GELU -----------------------
__global__ __launch_bounds__(256, 1) void attn_ln_gelu(
    const float* __restrict__ x, const bf16* __restrict__ wt,
    const float* __restrict__ gamma, const float* __restrict__ beta,
    float* __restrict__ out) {
  __shared__ uint4 ldsbuf[6144];            // 96 KB: 3 x 32KB tiles
  char* t_x = (char*)ldsbuf;                // Xb -> Q -> O
  char* t_k = t_x + 32768;                  // K  -> P
  char* t_v = t_k + 32768;                  // V^T

  const int tid = threadIdx.x;
  const int wave = tid >> 6, lane = tid & 63;
  const int l15 = lane & 15, quad = lane >> 4;
  const int row0 = wave * 32;
  const int g = blockIdx.x;
  const int b = g >> 6, blk = g & 63;
  const float* xb = x + ((size_t)b * S_ + (size_t)blk * 128) * D_;
  float* outb = out + ((size_t)b * 2 * S_ + (size_t)blk * 128) * D_;

  // ---- stage Xb (fp32, 64KB global) as bf16 into swizzled LDS
  for (int i = 0; i < 8; ++i) {
    int e = (tid + i * 256) * 8;            // element index 0..16383
    float4 f0 = *(const float4*)(xb + e);
    float4 f1 = *(const float4*)(xb + e + 4);
    bf16 tmp[8];
    tmp[0] = __float2bfloat16(f0.x); tmp[1] = __float2bfloat16(f0.y);
    tmp[2] = __float2bfloat16(f0.z); tmp[3] = __float2bfloat16(f0.w);
    tmp[4] = __float2bfloat16(f1.x); tmp[5] = __float2bfloat16(f1.y);
    tmp[6] = __float2bfloat16(f1.z); tmp[7] = __float2bfloat16(f1.w);
    int r = e >> 7, c = (e >> 3) & 15;
    *(uint4*)(t_x + sw(r, c)) = *(const uint4*)tmp;
  }
  __syncthreads();

  f32x4 acc[2][8];

  // ---- K = Xb @ Wk
  clr(acc);
  mm_g16(t_x, (const char*)(wt + 16384), row0, lane, acc);
  store_tile16(t_k, row0, lane, acc, nullptr);

  // ---- V = Xb @ Wv, stored transposed
  clr(acc);
  mm_g16(t_x, (const char*)(wt + 2 * 16384), row0, lane, acc);
  store_tileT16(t_v, row0, lane, acc);

  // ---- Q = Xb @ Wq (held in acc across the barrier)
  clr(acc);
  mm_g16(t_x, (const char*)(wt + 0), row0, lane, acc);
  __syncthreads();                          // everyone done with Xb; K,V^T visible
  store_tile16(t_x, row0, lane, acc, nullptr);   // overwrite Xb with Q (own rows)

  // ---- S = Q @ K^T  (B-frag of K^T == A-style read of K)
  clr(acc);
  mm_l16(t_x, t_k, row0, lane, acc);

  // ---- row softmax (rows live in 16-lane groups x 8 col-tiles)
  float inv[8];
  const float sscale = 0.08838834764831845f;   // 1/sqrt(128)
#pragma unroll
  for (int rt = 0; rt < 2; ++rt)
#pragma unroll
    for (int r = 0; r < 4; ++r) {
      float v[8]; float m = -1e30f;
#pragma unroll
      for (int ct = 0; ct < 8; ++ct) { v[ct] = acc[rt][ct][r] * sscale; m = fmaxf(m, v[ct]); }
#pragma unroll
      for (int off = 8; off; off >>= 1) m = fmaxf(m, __shfl_xor(m, off, 64));
      float sum = 0.f;
#pragma unroll
      for (int ct = 0; ct < 8; ++ct) { v[ct] = expf(v[ct] - m); sum += v[ct]; }
#pragma unroll
      for (int off = 8; off; off >>= 1) sum += __shfl_xor(sum, off, 64);
      inv[rt * 4 + r] = 1.0f / sum;
#pragma unroll
      for (int ct = 0; ct < 8; ++ct) acc[rt][ct][r] = v[ct];
    }
  __syncthreads();                          // all waves done reading K
  store_tile16(t_k, row0, lane, acc, nullptr);   // P (unnormalized) over K

  // ---- O = P @ V  (A = own P rows, B = V^T), fold 1/rowsum
  clr(acc);
  mm_l16(t_k, t_v, row0, lane, acc);
  store_tile16(t_x, row0, lane, acc, inv);  // O over Q (own rows only)

  // ---- H = O @ Wo
  clr(acc);
  mm_g16(t_x, (const char*)(wt + 3 * 16384), row0, lane, acc);

  // ---- LayerNorm + exact GELU, straight to global (fp32)
  float gg[8], bbv[8];
#pragma unroll
  for (int ct = 0; ct < 8; ++ct) {
    gg[ct] = gamma[ct * 16 + l15];
    bbv[ct] = beta[ct * 16 + l15];
  }
#pragma unroll
  for (int rt = 0; rt < 2; ++rt)
#pragma unroll
    for (int r = 0; r < 4; ++r) {
      float sum = 0.f;
#pragma unroll
      for (int ct = 0; ct < 8; ++ct) sum += acc[rt][ct][r];
#pragma unroll
      for (int off = 8; off; off >>= 1) sum += __shfl_xor(sum, off, 64);
      float mean = sum * (1.0f / 128.0f);
      float sq = 0.f;
#pragma unroll
      for (int ct = 0; ct < 8; ++ct) { float d = acc[rt][ct][r] - mean; sq += d * d; }
#pragma unroll
      for (int off = 8; off; off >>= 1) sq += __shfl_xor(sq, off, 64);
      float rstd = rsqrtf(sq * (1.0f / 128.0f) + 1e-5f);
      int row = row0 + rt * 16 + quad * 4 + r;
      float* op = outb + (size_t)row * 128;
#pragma unroll
      for (int ct = 0; ct < 8; ++ct) {
        float y = (acc[rt][ct][r] - mean) * rstd * gg[ct] + bbv[ct];
        op[ct * 16 + l15] = gelu_exact(y);
      }
    }
}

extern "C" void kernel_launch(void* const* d_in, const int* in_sizes, int n_in,
                              void* d_out, int out_size, void* d_ws, size_t ws_size,
                              hipStream_t stream) {
  const float* x     = (const float*)d_in[0];
  const float* wq    = (const float*)d_in[1];
  const float* wk    = (const float*)d_in[2];
  const float* wv    = (const float*)d_in[3];
  const float* wo    = (const float*)d_in[4];
  const float* gamma = (const float*)d_in[5];
  const float* beta  = (const float*)d_in[6];
  float* out = (float*)d_out;
  bf16* wt  = (bf16*)d_ws;                  // 4 x 128 x 128 bf16 = 128 KB

  transw<<<4, 256, 0, stream>>>(wq, wk, wv, wo, wt);
  fill2<<<4096, 256, 0, stream>>>(beta, out);
  attn_ln_gelu<<<512, 256, 0, stream>>>(x, wt, gamma, beta, out);
}